// Round 1
// baseline (16163.722 us; speedup 1.0000x reference)
//
#include <hip/hip_runtime.h>

#define N_USERS 100000
#define N_ITEMS 50000
#define N_NODES 150000   // N_USERS + N_ITEMS
#define DIM 64
#define NQ 4096

// ---------------- concat user_emb + item_emb into one [N_NODES][DIM] buffer ----
__global__ void k_concat(const float* __restrict__ ue, const float* __restrict__ ie,
                         float* __restrict__ emb) {
    int i = blockIdx.x * blockDim.x + threadIdx.x;   // float4 index
    const int totalU = N_USERS * DIM / 4;
    const int total  = N_NODES * DIM / 4;
    if (i >= total) return;
    float4 v = (i < totalU) ? ((const float4*)ue)[i] : ((const float4*)ie)[i - totalU];
    ((float4*)emb)[i] = v;
}

// ---------------- scatter SpMM: y[src] += val * x[dst] --------------------------
// 16 threads per edge, each handles 4 dims (float4 load, 4x atomicAdd)
__global__ void k_spmm(const int* __restrict__ src, const int* __restrict__ dst,
                       const float* __restrict__ val, const float* __restrict__ x,
                       float* __restrict__ y, int nE) {
    int t = blockIdx.x * blockDim.x + threadIdx.x;
    int e = t >> 4;
    int k = t & 15;
    if (e >= nE) return;
    int   s = src[e];
    int   d = dst[e];
    float v = val[e];
    float4 xv = ((const float4*)x)[(size_t)d * 16 + k];
    float* yp = y + (size_t)s * DIM + k * 4;
    atomicAdd(yp + 0, v * xv.x);
    atomicAdd(yp + 1, v * xv.y);
    atomicAdd(yp + 2, v * xv.z);
    atomicAdd(yp + 3, v * xv.w);
}

// ---------------- gather selected rows into small acc buffer -------------------
// rows 0..NQ-1: users, rows NQ..2NQ-1: items (+N_USERS offset)
__global__ void k_gather(const int* __restrict__ users, const int* __restrict__ items,
                         const float* __restrict__ emb, float* __restrict__ acc,
                         int init) {
    int t = blockIdx.x * blockDim.x + threadIdx.x;   // (row, k) with k = float4 idx
    int r = t >> 4;
    int k = t & 15;
    if (r >= 2 * NQ) return;
    int node = (r < NQ) ? users[r] : (N_USERS + items[r - NQ]);
    float4 v = ((const float4*)emb)[(size_t)node * 16 + k];
    float4* a = ((float4*)acc) + (size_t)r * 16 + k;
    if (init) {
        *a = v;
    } else {
        float4 c = *a;
        c.x += v.x; c.y += v.y; c.z += v.z; c.w += v.w;
        *a = c;
    }
}

// ---------------- final dot: gamma[i] = dot(acc_u[i], acc_v[i]) / 16 -----------
__global__ void k_dot(const float* __restrict__ acc, float* __restrict__ out) {
    int i = blockIdx.x * blockDim.x + threadIdx.x;
    if (i >= NQ) return;
    const float* u = acc + (size_t)i * DIM;
    const float* v = acc + (size_t)(NQ + i) * DIM;
    float s = 0.f;
#pragma unroll
    for (int d = 0; d < DIM; ++d) s += u[d] * v[d];
    out[i] = s * (1.0f / 16.0f);   // (acc/4)·(acc/4)
}

extern "C" void kernel_launch(void* const* d_in, const int* in_sizes, int n_in,
                              void* d_out, int out_size, void* d_ws, size_t ws_size,
                              hipStream_t stream) {
    const float* ue   = (const float*)d_in[0];
    const float* ie   = (const float*)d_in[1];
    const int*   esrc = (const int*)d_in[2];
    const int*   edst = (const int*)d_in[3];
    const float* ev   = (const float*)d_in[4];
    const int*   users = (const int*)d_in[5];
    const int*   items = (const int*)d_in[6];
    float* out = (float*)d_out;
    const int nE = in_sizes[2];

    const size_t embBytes = (size_t)N_NODES * DIM * sizeof(float);  // 38.4 MB
    float* emb0 = (float*)d_ws;
    float* emb1 = (float*)((char*)d_ws + embBytes);
    float* acc  = (float*)((char*)d_ws + 2 * embBytes);             // 8192*64 f32

    // layer-0 embedding
    const int totalV4 = N_NODES * DIM / 4;
    k_concat<<<(totalV4 + 255) / 256, 256, 0, stream>>>(ue, ie, emb0);
    // acc = layer-0 rows at the queried nodes
    k_gather<<<(2 * NQ * 16 + 255) / 256, 256, 0, stream>>>(users, items, emb0, acc, 1);

    float* cur = emb0;
    float* nxt = emb1;
    for (int l = 0; l < 3; ++l) {
        hipMemsetAsync(nxt, 0, embBytes, stream);
        long threads = (long)nE * 16;
        k_spmm<<<(int)((threads + 255) / 256), 256, 0, stream>>>(esrc, edst, ev, cur, nxt, nE);
        k_gather<<<(2 * NQ * 16 + 255) / 256, 256, 0, stream>>>(users, items, nxt, acc, 0);
        float* tmp = cur; cur = nxt; nxt = tmp;
    }

    k_dot<<<(NQ + 255) / 256, 256, 0, stream>>>(acc, out);
}

// Round 2
// 1572.782 us; speedup vs baseline: 10.2772x; 10.2772x over previous
//
#include <hip/hip_runtime.h>

#define N_USERS 100000
#define N_ITEMS 50000
#define N_NODES 150000   // N_USERS + N_ITEMS
#define DIM 64
#define NQ 4096

static inline size_t align256(size_t x) { return (x + 255) & ~(size_t)255; }

// ---------------- concat user_emb + item_emb into one [N_NODES][DIM] buffer ----
__global__ void k_concat(const float* __restrict__ ue, const float* __restrict__ ie,
                         float* __restrict__ emb) {
    int i = blockIdx.x * blockDim.x + threadIdx.x;   // float4 index
    const int totalU = N_USERS * DIM / 4;
    const int total  = N_NODES * DIM / 4;
    if (i >= total) return;
    float4 v = (i < totalU) ? ((const float4*)ue)[i] : ((const float4*)ie)[i - totalU];
    ((float4*)emb)[i] = v;
}

// ---------------- CSR build: histogram ----------------------------------------
__global__ void k_hist(const int* __restrict__ src, int* __restrict__ cnt, int nE) {
    int e = blockIdx.x * blockDim.x + threadIdx.x;
    if (e < nE) atomicAdd(&cnt[src[e]], 1);
}

// ---------------- CSR build: exclusive prefix sum (single block) ---------------
__global__ void k_scan(const int* __restrict__ cnt, int* __restrict__ rowptr) {
    __shared__ int wsum[16];
    __shared__ int aux[17];   // [0..15] exclusive wave offsets, [16] chunk total
    int tid  = threadIdx.x;
    int lane = tid & 63;
    int wid  = tid >> 6;
    int carry = 0;
    for (int base = 0; base < N_NODES; base += 1024) {
        int idx = base + tid;
        int v = (idx < N_NODES) ? cnt[idx] : 0;
        int x = v;
#pragma unroll
        for (int off = 1; off < 64; off <<= 1) {
            int t = __shfl_up(x, off);
            if (lane >= off) x += t;
        }
        if (lane == 63) wsum[wid] = x;
        __syncthreads();
        if (wid == 0) {
            int s = (lane < 16) ? wsum[lane] : 0;
            int y = s;
#pragma unroll
            for (int off = 1; off < 16; off <<= 1) {
                int t = __shfl_up(y, off);
                if (lane >= off) y += t;
            }
            if (lane < 16) aux[lane] = y - s;   // exclusive offset
            if (lane == 15) aux[16] = y;        // chunk total
        }
        __syncthreads();
        if (idx < N_NODES) rowptr[idx] = carry + aux[wid] + x - v;  // exclusive
        carry += aux[16];
        __syncthreads();   // wsum/aux reused next chunk
    }
    if (tid == 0) rowptr[N_NODES] = carry;
}

// ---------------- CSR build: scatter edges into bins ---------------------------
__global__ void k_scatter(const int* __restrict__ src, const int* __restrict__ dst,
                          const float* __restrict__ val, int* __restrict__ cursor,
                          int* __restrict__ cdst, float* __restrict__ cval, int nE) {
    int e = blockIdx.x * blockDim.x + threadIdx.x;
    if (e >= nE) return;
    int s = src[e];
    int pos = atomicAdd(&cursor[s], 1);
    cdst[pos] = dst[e];
    cval[pos] = val[e];
}

// ---------------- gather SpMM: y[r] = sum_e val[e] * x[dst[e]] -----------------
// one wave per row; 4 edges in flight (quarter-wave each), float4 per lane
__global__ void k_spmm_csr(const int* __restrict__ rowptr, const int* __restrict__ cdst,
                           const float* __restrict__ cval, const float* __restrict__ x,
                           float* __restrict__ y) {
    int gw   = (blockIdx.x * blockDim.x + threadIdx.x) >> 6;  // row (node)
    int lane = threadIdx.x & 63;
    if (gw >= N_NODES) return;
    int beg = rowptr[gw], end = rowptr[gw + 1];
    int q = lane >> 4;    // which of 4 concurrent edges
    int k = lane & 15;    // float4 index within the 64-dim row
    float4 acc = make_float4(0.f, 0.f, 0.f, 0.f);
    for (int p = beg; p + q < end; p += 4) {
        int   e = p + q;
        int   d = cdst[e];
        float v = cval[e];
        float4 xv = ((const float4*)x)[(size_t)d * 16 + k];
        acc.x += v * xv.x; acc.y += v * xv.y; acc.z += v * xv.z; acc.w += v * xv.w;
    }
#pragma unroll
    for (int off = 16; off < 64; off <<= 1) {
        acc.x += __shfl_xor(acc.x, off);
        acc.y += __shfl_xor(acc.y, off);
        acc.z += __shfl_xor(acc.z, off);
        acc.w += __shfl_xor(acc.w, off);
    }
    if (lane < 16) ((float4*)y)[(size_t)gw * 16 + k] = acc;
}

// ---------------- fallback scatter SpMM (atomics) ------------------------------
__global__ void k_spmm_atomic(const int* __restrict__ src, const int* __restrict__ dst,
                              const float* __restrict__ val, const float* __restrict__ x,
                              float* __restrict__ y, int nE) {
    int t = blockIdx.x * blockDim.x + threadIdx.x;
    int e = t >> 4;
    int k = t & 15;
    if (e >= nE) return;
    int   s = src[e];
    int   d = dst[e];
    float v = val[e];
    float4 xv = ((const float4*)x)[(size_t)d * 16 + k];
    float* yp = y + (size_t)s * DIM + k * 4;
    atomicAdd(yp + 0, v * xv.x);
    atomicAdd(yp + 1, v * xv.y);
    atomicAdd(yp + 2, v * xv.z);
    atomicAdd(yp + 3, v * xv.w);
}

// ---------------- gather selected rows into small acc buffer -------------------
__global__ void k_gather(const int* __restrict__ users, const int* __restrict__ items,
                         const float* __restrict__ emb, float* __restrict__ acc,
                         int init) {
    int t = blockIdx.x * blockDim.x + threadIdx.x;
    int r = t >> 4;
    int k = t & 15;
    if (r >= 2 * NQ) return;
    int node = (r < NQ) ? users[r] : (N_USERS + items[r - NQ]);
    float4 v = ((const float4*)emb)[(size_t)node * 16 + k];
    float4* a = ((float4*)acc) + (size_t)r * 16 + k;
    if (init) {
        *a = v;
    } else {
        float4 c = *a;
        c.x += v.x; c.y += v.y; c.z += v.z; c.w += v.w;
        *a = c;
    }
}

// ---------------- final dot: gamma[i] = dot(acc_u[i], acc_v[i]) / 16 -----------
__global__ void k_dot(const float* __restrict__ acc, float* __restrict__ out) {
    int i = blockIdx.x * blockDim.x + threadIdx.x;
    if (i >= NQ) return;
    const float* u = acc + (size_t)i * DIM;
    const float* v = acc + (size_t)(NQ + i) * DIM;
    float s = 0.f;
#pragma unroll
    for (int d = 0; d < DIM; ++d) s += u[d] * v[d];
    out[i] = s * (1.0f / 16.0f);   // (acc/4)·(acc/4)
}

extern "C" void kernel_launch(void* const* d_in, const int* in_sizes, int n_in,
                              void* d_out, int out_size, void* d_ws, size_t ws_size,
                              hipStream_t stream) {
    const float* ue    = (const float*)d_in[0];
    const float* ie    = (const float*)d_in[1];
    const int*   esrc  = (const int*)d_in[2];
    const int*   edst  = (const int*)d_in[3];
    const float* ev    = (const float*)d_in[4];
    const int*   users = (const int*)d_in[5];
    const int*   items = (const int*)d_in[6];
    float* out = (float*)d_out;
    const int nE = in_sizes[2];

    const size_t embB = (size_t)N_NODES * DIM * sizeof(float);   // 38.4 MB
    const size_t accB = (size_t)2 * NQ * DIM * sizeof(float);    // 2 MB
    const size_t rpB  = (size_t)(N_NODES + 1) * sizeof(int);
    const size_t cntB = (size_t)N_NODES * sizeof(int);
    const size_t cdB  = (size_t)nE * sizeof(int);
    const size_t cvB  = (size_t)nE * sizeof(float);

    size_t o = 0;
    char* base = (char*)d_ws;
    float* emb0  = (float*)(base + o); o = align256(o + embB);
    float* emb1  = (float*)(base + o); o = align256(o + embB);
    float* acc   = (float*)(base + o); o = align256(o + accB);
    int*   rowp  = (int*)  (base + o); o = align256(o + rpB);
    int*   cnt   = (int*)  (base + o); o = align256(o + cntB);   // doubles as cursor
    int*   cdst  = (int*)  (base + o); o = align256(o + cdB);
    float* cval  = (float*)(base + o); o = align256(o + cvB);
    const bool csr_ok = (o <= ws_size);

    const int totalV4 = N_NODES * DIM / 4;
    k_concat<<<(totalV4 + 255) / 256, 256, 0, stream>>>(ue, ie, emb0);
    k_gather<<<(2 * NQ * 16 + 255) / 256, 256, 0, stream>>>(users, items, emb0, acc, 1);

    if (csr_ok) {
        // ---- build CSR ----
        hipMemsetAsync(cnt, 0, cntB, stream);
        k_hist<<<(nE + 255) / 256, 256, 0, stream>>>(esrc, cnt, nE);
        k_scan<<<1, 1024, 0, stream>>>(cnt, rowp);
        hipMemcpyAsync(cnt, rowp, cntB, hipMemcpyDeviceToDevice, stream); // cursor = rowptr
        k_scatter<<<(nE + 255) / 256, 256, 0, stream>>>(esrc, edst, ev, cnt, cdst, cval, nE);

        // ---- 3 propagation layers ----
        float* cur = emb0;
        float* nxt = emb1;
        const int spmmBlocks = (N_NODES * 64 + 255) / 256;
        for (int l = 0; l < 3; ++l) {
            k_spmm_csr<<<spmmBlocks, 256, 0, stream>>>(rowp, cdst, cval, cur, nxt);
            k_gather<<<(2 * NQ * 16 + 255) / 256, 256, 0, stream>>>(users, items, nxt, acc, 0);
            float* tmp = cur; cur = nxt; nxt = tmp;
        }
    } else {
        // ---- fallback: atomic scatter path (verified round 1) ----
        float* cur = emb0;
        float* nxt = emb1;
        for (int l = 0; l < 3; ++l) {
            hipMemsetAsync(nxt, 0, embB, stream);
            long threads = (long)nE * 16;
            k_spmm_atomic<<<(int)((threads + 255) / 256), 256, 0, stream>>>(esrc, edst, ev, cur, nxt, nE);
            k_gather<<<(2 * NQ * 16 + 255) / 256, 256, 0, stream>>>(users, items, nxt, acc, 0);
            float* tmp = cur; cur = nxt; nxt = tmp;
        }
    }

    k_dot<<<(NQ + 255) / 256, 256, 0, stream>>>(acc, out);
}